// Round 13
// baseline (1613.832 us; speedup 1.0000x reference)
//
#include <hip/hip_runtime.h>
#include <hip/hip_fp16.h>
#include <cstddef>

#define TPB 256
#define BSH 7            // log2(targets per bucket) — 782 buckets
#define BTGT 128         // targets per bucket
#define EPA 16           // edges per thread in scatter
#define ACHUNK (EPA * TPB)
#define LSTR 136         // LDS h-tile row stride in halves (272 B: 2-way max)
#define CAP 2560         // padded slots per bucket (mean 2048, +6 sigma)
#define NBMAX 1024       // compile-time bucket-count bound
#define GGRID 1024       // gemm12 grid
#define GTPB 512         // gather block threads (8 waves)

typedef _Float16 f16x8 __attribute__((ext_vector_type(8)));
typedef float    f32x4 __attribute__((ext_vector_type(4)));

// ===========================================================================
// Bucket scatter + degree accumulation.  recs[b*CAP+slot] =
// {(t_local<<23)|(src<<6)|flag, bitcast(w)} (w RAW — no ordering pass needed
// anymore).  Degrees via global fp32 atomics on L2-resident degP/degN.
// ===========================================================================
__global__ __launch_bounds__(256) void bucket_scatter_kernel(
        const int* __restrict__ tgt, const int* __restrict__ src,
        const float* __restrict__ ew, int* __restrict__ cnt_pad,
        float* __restrict__ degP, float* __restrict__ degN,
        int2* __restrict__ recs, int nb, int E) {
    __shared__ int lcnt[NBMAX];
    __shared__ int lbase[NBMAX];
    const int tid = threadIdx.x;
    for (int i = tid; i < nb; i += 256) lcnt[i] = 0;
    __syncthreads();
    const int base = blockIdx.x * ACHUNK + tid;
    int px[EPA], pw[EPA], mr[EPA], mb[EPA];
#pragma unroll
    for (int j = 0; j < EPA; ++j) {
        int e = base + j * TPB;
        if (e < E) {
            int t = tgt[e], s = src[e];
            float w = ew[e];
            int flag = (w < 0.0f) ? 1 : 0;
            mb[j] = t >> BSH;
            px[j] = ((t & (BTGT - 1)) << 23) | (s << 6) | flag;
            pw[j] = __float_as_int(w);
            mr[j] = atomicAdd(&lcnt[mb[j]], 1);
            if (flag)            atomicAdd(&degN[t], -w);
            else if (w > 0.0f)   atomicAdd(&degP[t], w);
        }
    }
    __syncthreads();
    for (int i = tid; i < nb; i += 256)
        if (lcnt[i]) lbase[i] = atomicAdd(&cnt_pad[i * 16], lcnt[i]);
    __syncthreads();
#pragma unroll
    for (int j = 0; j < EPA; ++j) {
        int e = base + j * TPB;
        if (e < E) {
            int sl = lbase[mb[j]] + mr[j];
            if (sl < CAP)                       // overflow guard (never hit)
                recs[(size_t)mb[j] * CAP + sl] = make_int2(px[j], pw[j]);
        }
    }
}

// ===========================================================================
// prep: node-parallel dinv + xs = [x*dp | x*dn] (fp16) + weight convert.
// Fully coalesced, full occupancy — replaces csr_build's serial tail work.
// ===========================================================================
__global__ __launch_bounds__(256) void prep_kernel(
        const float* __restrict__ x,
        const float* __restrict__ degP, const float* __restrict__ degN,
        float* __restrict__ dinvp, float* __restrict__ dinvn,
        const float* __restrict__ W1p, const float* __restrict__ W1n,
        const float* __restrict__ W2p, const float* __restrict__ W2n,
        __half* __restrict__ xs, __half* __restrict__ w16, int n) {
    int idx = blockIdx.x * blockDim.x + threadIdx.x;
    int npx = n * 32;
    if (idx < npx) {
        int row = idx >> 5, jp = idx & 31;
        float dp = rsqrtf(degP[row] + 1.0f);
        float dn = rsqrtf(degN[row] + 1.0f);
        if (jp == 0) { dinvp[row] = dp; dinvn[row] = dn; }
        float2 v = *(const float2*)(x + (size_t)row * 64 + jp * 2);
        __half2* xr = (__half2*)(xs + (size_t)row * 128);
        xr[jp]      = __floats2half2_rn(v.x * dp, v.y * dp);
        xr[jp + 32] = __floats2half2_rn(v.x * dn, v.y * dn);
    } else {
        int q = idx - npx;
        if (q < 16384) {
            const float* Wsrc = (q < 4096) ? W1p : (q < 8192) ? W1n
                              : (q < 12288) ? W2p : W2n;
            float2 v = *(const float2*)(Wsrc + (size_t)(q & 4095) * 2);
            ((__half2*)w16)[q] = __floats2half2_rn(v.x, v.y);
        }
    }
}

// ===========================================================================
// gatherL1: EDGE-PARALLEL layer-1 aggregation — needs NO target ordering.
// Block = 1 bucket; acc[128 tgt][128 feat] fp32 in LDS (64 KB); each wave
// sweeps 64 recs per 512-chunk, batch-8: 8 broadcast rbuf reads -> 8 random
// 128-B xs half-row loads -> 8 conflict-free LDS float atomics.
// Epilogue: aggP = dp*(accP + xsP[t]); aggN = dn*(accN - xsN[t]).
// ===========================================================================
__global__ __launch_bounds__(512) void gatherL1_kernel(
        const int* __restrict__ cnt_pad, const int2* __restrict__ recs,
        const __half* __restrict__ xs,
        const float* __restrict__ dinvp, const float* __restrict__ dinvn,
        __half* __restrict__ agg, int n) {
    __shared__ float acc[BTGT * 128];
    __shared__ int2  rbuf[GTPB];
    const int b = blockIdx.x, tid = threadIdx.x;
    const int lane = tid & 63, wv = tid >> 6;
    int cnt = cnt_pad[b * 16]; if (cnt > CAP) cnt = CAP;
    const int t0 = b << BSH;
    for (int i = tid; i < BTGT * 128; i += GTPB) acc[i] = 0.f;
    __syncthreads();
    const int2* rb = recs + (size_t)b * CAP;
    for (int cbase = 0; cbase < cnt; cbase += GTPB) {
        const int m = min(GTPB, cnt - cbase);
        if (tid < m) rbuf[tid] = rb[cbase + tid];
        __syncthreads();
        const int lo = wv * 64;
        const int hi = (lo + 64 < m) ? lo + 64 : m;
        int k = lo;
        for (; k + 7 < hi; k += 8) {
            float w[8], xv[8]; int ai[8];
#pragma unroll
            for (int j = 0; j < 8; ++j) {
                int2 r = rbuf[k + j];
                int s  = (r.x >> 6) & 0x1FFFF;
                int fo = (r.x & 1) << 6;
                int tl = ((unsigned)r.x) >> 23;
                w[j]  = __int_as_float(r.y);
                ai[j] = tl * 128 + fo + lane;
                xv[j] = __half2float(xs[(size_t)s * 128 + fo + lane]);
            }
#pragma unroll
            for (int j = 0; j < 8; ++j)
                atomicAdd(&acc[ai[j]], w[j] * xv[j]);
        }
        for (; k < hi; ++k) {
            int2 r = rbuf[k];
            int s  = (r.x >> 6) & 0x1FFFF;
            int fo = (r.x & 1) << 6;
            int tl = ((unsigned)r.x) >> 23;
            float w = __int_as_float(r.y);
            float xv = __half2float(xs[(size_t)s * 128 + fo + lane]);
            atomicAdd(&acc[tl * 128 + fo + lane], w * xv);
        }
        __syncthreads();
    }
    for (int j = wv; j < BTGT; j += 8) {
        int t = t0 + j;
        if (t >= n) break;
        float dp = dinvp[t], dn = dinvn[t];
        float xp = __half2float(xs[(size_t)t * 128 + lane]);
        float xn = __half2float(xs[(size_t)t * 128 + 64 + lane]);
        float accP = dp * (acc[j * 128 + lane] + xp);
        float accN = dn * (acc[j * 128 + 64 + lane] - xn);
        __builtin_nontemporal_store(__half_as_ushort((__half)accP),
            (unsigned short*)(agg + (size_t)t * 128 + lane));
        __builtin_nontemporal_store(__half_as_ushort((__half)accN),
            (unsigned short*)(agg + (size_t)t * 128 + 64 + lane));
    }
}

// ===========================================================================
// gemm12: fused dual-layer GEMM, B-resident (round-9 verified structure).
// g2 ALIASES agg (row-local; agg reads precede g2 writes) — no __restrict__.
// ===========================================================================
__global__ __launch_bounds__(256, 2) void gemm12_mfma(
        const __half* agg,
        const __half* __restrict__ w1p, const __half* __restrict__ w1n,
        const float* __restrict__ b1p, const float* __restrict__ b1n,
        const __half* __restrict__ w2p, const __half* __restrict__ w2n,
        const float* __restrict__ dinvp, const float* __restrict__ dinvn,
        __half* g2, int n) {
    __shared__ _Float16 T[16 * LSTR];
    const int lane = threadIdx.x & 63;
    const int wv = threadIdx.x >> 6;
    const int m = lane & 15, quad = lane >> 4;
    const int t0 = 2 * wv, t1 = t0 + 1;      // this wave's two col-tiles
    const int ntile = (n + 15) >> 4;

    f16x8 B1a[4], B1b[4], B2a[4], B2b[4];
    const __half* W2 = (t0 < 4) ? w2p : w2n;
#pragma unroll
    for (int kc = 0; kc < 4; ++kc) {
        const __half* W1 = (kc < 2) ? w1p : w1n;
        const int ko = (kc & 1) * 32 + quad * 8;
        B1a[kc] = *(const f16x8*)(W1 + (size_t)(t0 * 16 + m) * 64 + ko);
        B1b[kc] = *(const f16x8*)(W1 + (size_t)(t1 * 16 + m) * 64 + ko);
        B2a[kc] = *(const f16x8*)(W2 + (size_t)((t0 & 3) * 16 + m) * 128 + kc * 32 + quad * 8);
        B2b[kc] = *(const f16x8*)(W2 + (size_t)((t1 & 3) * 16 + m) * 128 + kc * 32 + quad * 8);
    }
    const float bd0 = b1p[t0 * 16 + m] - b1n[t0 * 16 + m];
    const float bd1 = b1p[t1 * 16 + m] - b1n[t1 * 16 + m];

    int tile = blockIdx.x;
    f16x8 a1c[4];
    if (tile < ntile) {
        int arow = tile * 16 + m; if (arow > n - 1) arow = n - 1;
#pragma unroll
        for (int kc = 0; kc < 4; ++kc)
            a1c[kc] = *(const f16x8*)(agg + (size_t)arow * 128 + kc * 32 + quad * 8);
    }

    for (; tile < ntile; tile += gridDim.x) {
        const int row0 = tile * 16;
        f32x4 acc0 = (f32x4){0.f, 0.f, 0.f, 0.f};
        f32x4 acc1 = (f32x4){0.f, 0.f, 0.f, 0.f};
#pragma unroll
        for (int kc = 0; kc < 4; ++kc) {
            acc0 = __builtin_amdgcn_mfma_f32_16x16x32_f16(a1c[kc], B1a[kc], acc0, 0, 0, 0);
            acc1 = __builtin_amdgcn_mfma_f32_16x16x32_f16(a1c[kc], B1b[kc], acc1, 0, 0, 0);
        }
        float sp[4], sn[4]; int rows[4];
#pragma unroll
        for (int r = 0; r < 4; ++r) {
            int rw = row0 + quad * 4 + r;
            rows[r] = rw;
            sp[r] = (rw < n) ? dinvp[rw] : 0.f;
            sn[r] = (rw < n) ? dinvn[rw] : 0.f;
        }
#pragma unroll
        for (int r = 0; r < 4; ++r) {
            T[(quad * 4 + r) * LSTR + t0 * 16 + m] = (_Float16)fmaxf(acc0[r] + bd0, 0.f);
            T[(quad * 4 + r) * LSTR + t1 * 16 + m] = (_Float16)fmaxf(acc1[r] + bd1, 0.f);
        }
        const int ntile_i = tile + gridDim.x;
        f16x8 a1nx[4];
        if (ntile_i < ntile) {
            int arow = ntile_i * 16 + m; if (arow > n - 1) arow = n - 1;
#pragma unroll
            for (int kc = 0; kc < 4; ++kc)
                a1nx[kc] = *(const f16x8*)(agg + (size_t)arow * 128 + kc * 32 + quad * 8);
        }
        __syncthreads();
        f16x8 a2[4];
#pragma unroll
        for (int kc = 0; kc < 4; ++kc)
            a2[kc] = *(const f16x8*)(T + m * LSTR + kc * 32 + quad * 8);
        __syncthreads();
        f32x4 c0 = (f32x4){0.f, 0.f, 0.f, 0.f};
        f32x4 c1 = (f32x4){0.f, 0.f, 0.f, 0.f};
#pragma unroll
        for (int kc = 0; kc < 4; ++kc) {
            c0 = __builtin_amdgcn_mfma_f32_16x16x32_f16(a2[kc], B2a[kc], c0, 0, 0, 0);
            c1 = __builtin_amdgcn_mfma_f32_16x16x32_f16(a2[kc], B2b[kc], c1, 0, 0, 0);
        }
        const float* dsel0 = (t0 < 4) ? sp : sn;
#pragma unroll
        for (int r = 0; r < 4; ++r)
            if (rows[r] < n) {
                g2[(size_t)rows[r] * 128 + t0 * 16 + m] = (__half)(c0[r] * dsel0[r]);
                g2[(size_t)rows[r] * 128 + t1 * 16 + m] = (__half)(c1[r] * dsel0[r]);
            }
#pragma unroll
        for (int kc = 0; kc < 4; ++kc) a1c[kc] = a1nx[kc];
    }
}

// ===========================================================================
// gatherL2: EDGE-PARALLEL layer-2 aggregation from raw recs.
// acc[128 tgt][accP 64 | accN 64] fp32 in LDS.  Epilogue:
// out = relu(dp*(accP + g2P[t]) + dn*(accN - g2N[t]) + bp - bn).
// ===========================================================================
__global__ __launch_bounds__(512) void gatherL2_kernel(
        const int* __restrict__ cnt_pad, const int2* __restrict__ recs,
        const __half* __restrict__ g2,
        const float* __restrict__ dinvp, const float* __restrict__ dinvn,
        const float* __restrict__ bp, const float* __restrict__ bn,
        float* __restrict__ out, int n) {
    __shared__ float acc[BTGT * 128];
    __shared__ int2  rbuf[GTPB];
    const int b = blockIdx.x, tid = threadIdx.x;
    const int lane = tid & 63, wv = tid >> 6;
    int cnt = cnt_pad[b * 16]; if (cnt > CAP) cnt = CAP;
    const int t0 = b << BSH;
    for (int i = tid; i < BTGT * 128; i += GTPB) acc[i] = 0.f;
    __syncthreads();
    const int2* rb = recs + (size_t)b * CAP;
    for (int cbase = 0; cbase < cnt; cbase += GTPB) {
        const int m = min(GTPB, cnt - cbase);
        if (tid < m) rbuf[tid] = rb[cbase + tid];
        __syncthreads();
        const int lo = wv * 64;
        const int hi = (lo + 64 < m) ? lo + 64 : m;
        int k = lo;
        for (; k + 7 < hi; k += 8) {
            float w[8], gv[8]; int ai[8];
#pragma unroll
            for (int j = 0; j < 8; ++j) {
                int2 r = rbuf[k + j];
                int s  = (r.x >> 6) & 0x1FFFF;
                int fo = (r.x & 1) << 6;
                int tl = ((unsigned)r.x) >> 23;
                w[j]  = __int_as_float(r.y);
                ai[j] = tl * 128 + fo + lane;
                gv[j] = __half2float(g2[(size_t)s * 128 + fo + lane]);
            }
#pragma unroll
            for (int j = 0; j < 8; ++j)
                atomicAdd(&acc[ai[j]], w[j] * gv[j]);
        }
        for (; k < hi; ++k) {
            int2 r = rbuf[k];
            int s  = (r.x >> 6) & 0x1FFFF;
            int fo = (r.x & 1) << 6;
            int tl = ((unsigned)r.x) >> 23;
            float w = __int_as_float(r.y);
            float gv = __half2float(g2[(size_t)s * 128 + fo + lane]);
            atomicAdd(&acc[tl * 128 + fo + lane], w * gv);
        }
        __syncthreads();
    }
    const float bd = bp[lane] - bn[lane];
    for (int j = wv; j < BTGT; j += 8) {
        int t = t0 + j;
        if (t >= n) break;
        float dp = dinvp[t], dn = dinvn[t];
        float gp = __half2float(g2[(size_t)t * 128 + lane]);
        float gn = __half2float(g2[(size_t)t * 128 + 64 + lane]);
        float o = dp * (acc[j * 128 + lane] + gp)
                + dn * (acc[j * 128 + 64 + lane] - gn) + bd;
        __builtin_nontemporal_store(fmaxf(o, 0.f), out + (size_t)t * 64 + lane);
    }
}

// ---------------------------------------------------------------------------
extern "C" void kernel_launch(void* const* d_in, const int* in_sizes, int n_in,
                              void* d_out, int out_size, void* d_ws, size_t ws_size,
                              hipStream_t stream) {
    const float* x   = (const float*)d_in[0];
    const int*   ei  = (const int*)d_in[1];
    const float* ew  = (const float*)d_in[2];
    const float* W1p = (const float*)d_in[3];
    const float* b1p = (const float*)d_in[4];
    const float* W1n = (const float*)d_in[5];
    const float* b1n = (const float*)d_in[6];
    const float* W2p = (const float*)d_in[7];
    const float* b2p = (const float*)d_in[8];
    const float* W2n = (const float*)d_in[9];
    const float* b2n = (const float*)d_in[10];

    const int E = in_sizes[2];
    const int n = in_sizes[0] / 64;  // IN = 64
    const int nb = (n + BTGT - 1) >> BSH;     // 782 buckets
    const int* src = ei;
    const int* tgt = ei + E;

    // ws layout (4B units): cnt_pad[nb*16] | degP[n] | degN[n] | dinvp[n] |
    //   dinvn[n] | xs[64n] | w16[16384] | recs[2*nb*CAP] | agg[64n].
    //   g2 aliases agg.  edat ELIMINATED.  ~60 MB.
    int* wsi     = (int*)d_ws;
    int* cnt_pad = wsi;
    size_t o = (size_t)nb * 16;
    float* degP   = (float*)(wsi + o);  o += n;
    float* degN   = (float*)(wsi + o);  o += n;
    float* dinvp  = (float*)(wsi + o);  o += n;
    float* dinvn  = (float*)(wsi + o);  o += n;
    o = (o + 3) & ~(size_t)3;
    __half* xs  = (__half*)(wsi + o);   o += (size_t)n * 64;   // 128 halves/row
    __half* w16 = (__half*)(wsi + o);   o += 16384;
    __half* w1p16 = w16, *w1n16 = w16 + 8192, *w2p16 = w16 + 16384, *w2n16 = w16 + 24576;
    int2* recs = (int2*)(wsi + o);      o += 2 * (size_t)nb * CAP;
    __half* agg = (__half*)(wsi + o);   o += (size_t)n * 64;
    __half* g2  = agg;                  // aliased (row-local in gemm12)
    float*  out = (float*)d_out;

    // zero cnt_pad + degP + degN in one memset (contiguous)
    hipMemsetAsync(cnt_pad, 0, ((size_t)nb * 16 + 2 * (size_t)n) * sizeof(int), stream);

    const int gridA = (E + ACHUNK - 1) / ACHUNK;
    const int gridP = (n * 32 + 16384 + TPB - 1) / TPB;
    const int ntile = (n + 15) / 16;
    const int gridF = (ntile < GGRID) ? ntile : GGRID;

    bucket_scatter_kernel<<<gridA, TPB, 0, stream>>>(tgt, src, ew, cnt_pad,
                                                     degP, degN, recs, nb, E);
    prep_kernel<<<gridP, TPB, 0, stream>>>(x, degP, degN, dinvp, dinvn,
                                           W1p, W1n, W2p, W2n, xs, w16, n);
    gatherL1_kernel<<<nb, GTPB, 0, stream>>>(cnt_pad, recs, xs, dinvp, dinvn, agg, n);
    gemm12_mfma<<<gridF, TPB, 0, stream>>>(agg, w1p16, w1n16, b1p, b1n,
                                           w2p16, w2n16, dinvp, dinvn, g2, n);
    gatherL2_kernel<<<nb, GTPB, 0, stream>>>(cnt_pad, recs, g2, dinvp, dinvn,
                                             b2p, b2n, out, n);
}

// Round 14
// 276.200 us; speedup vs baseline: 5.8430x; 5.8430x over previous
//
#include <hip/hip_runtime.h>
#include <hip/hip_fp16.h>
#include <cstddef>

#define TPB 256
#define BSH 9            // log2(targets per bucket)
#define BTGT 512         // targets per bucket
#define EPA 16           // edges per thread in scatter
#define ACHUNK (EPA * TPB)
#define LSTR 136         // LDS h-tile row stride in halves (272 B: 2-way max)
#define CAP 10240        // padded slots per bucket (avg 8163, max ~8.6K)
#define GGRID 1024       // gemm12 grid (grid-stride over row-tiles)

typedef _Float16 f16x8 __attribute__((ext_vector_type(8)));
typedef float    f32x4 __attribute__((ext_vector_type(4)));

// ===========================================================================
// Scatter directly into padded per-bucket regions (no count/scan passes).
// rec (int2) = {(t_local<<23)|(src<<6)|flag, bitcast(w)} at recs[b*CAP+slot].
// ===========================================================================
__global__ __launch_bounds__(256) void bucket_scatter_kernel(
        const int* __restrict__ tgt, const int* __restrict__ src,
        const float* __restrict__ ew, int* __restrict__ cnt_pad,
        int2* __restrict__ recs, int E) {
    __shared__ int lcnt[256];
    __shared__ int lbase[256];
    const int tid = threadIdx.x;
    lcnt[tid] = 0;
    __syncthreads();
    const int base = blockIdx.x * ACHUNK + tid;
    int px[EPA], pw[EPA], mr[EPA], mb[EPA];
#pragma unroll
    for (int j = 0; j < EPA; ++j) {
        int e = base + j * TPB;
        if (e < E) {
            int t = tgt[e], s = src[e];
            float w = ew[e];
            int flag = (w < 0.0f) ? 1 : 0;
            mb[j] = t >> BSH;
            px[j] = ((t & (BTGT - 1)) << 23) | (s << 6) | flag;
            pw[j] = __float_as_int(w);
            mr[j] = atomicAdd(&lcnt[mb[j]], 1);
        }
    }
    __syncthreads();
    if (lcnt[tid]) lbase[tid] = atomicAdd(&cnt_pad[tid * 16], lcnt[tid]);
    __syncthreads();
#pragma unroll
    for (int j = 0; j < EPA; ++j) {
        int e = base + j * TPB;
        if (e < E) {
            int sl = lbase[mb[j]] + mr[j];
            if (sl < CAP)                       // overflow guard (never hit)
                recs[(size_t)mb[j] * CAP + sl] = make_int2(px[j], pw[j]);
        }
    }
}

// ===========================================================================
// Per-bucket CSR build + dinv + edat ONLY (converts moved to prep_kernel —
// they were ~37 MB of traffic plus a serial block-0 tail in a 196-block
// latency-bound kernel).  nv = w * dinv_sel[tgt];
// edat[slot] = {(src<<8)|(flag<<7)|flag, bitcast(nv)}; rowse[t] = {beg,end}.
// ===========================================================================
__global__ __launch_bounds__(512) void csr_build_kernel(
        const int* __restrict__ cnt_pad, const int2* __restrict__ recs,
        int2* __restrict__ rowse, int2* __restrict__ edat,
        float* __restrict__ dinvp, float* __restrict__ dinvn, int n) {
    __shared__ int   hcnt[BTGT];
    __shared__ int   cur[BTGT];
    __shared__ int   sm[BTGT];
    __shared__ float sdp[BTGT];
    __shared__ float sdn[BTGT];
    const int b = blockIdx.x, tid = threadIdx.x;
    int cnt = cnt_pad[b * 16]; if (cnt > CAP) cnt = CAP;
    const int beg = b * CAP, end = beg + cnt;
    hcnt[tid] = 0;
    sdp[tid] = 0.f;
    sdn[tid] = 0.f;
    __syncthreads();
    for (int i = beg + tid; i < end; i += 512) {
        int2 r = recs[i];
        int tl = ((unsigned)r.x) >> 23;
        atomicAdd(&hcnt[tl], 1);
        float w = __int_as_float(r.y);
        if (w > 0.0f)      atomicAdd(&sdp[tl], w);
        else if (w < 0.0f) atomicAdd(&sdn[tl], -w);
    }
    __syncthreads();
    int own = hcnt[tid];
    sm[tid] = own;
    __syncthreads();
#pragma unroll
    for (int off = 1; off < 512; off <<= 1) {
        int add = (tid >= off) ? sm[tid - off] : 0;
        __syncthreads();
        sm[tid] += add;
        __syncthreads();
    }
    int excl = sm[tid] - own;
    cur[tid] = beg + excl;
    const int t = (b << BSH) + tid;
    if (t < n) {
        rowse[t] = make_int2(beg + excl, beg + excl + own);
        float dp = rsqrtf(sdp[tid] + 1.0f);
        float dn = rsqrtf(sdn[tid] + 1.0f);
        dinvp[t] = dp; dinvn[t] = dn;
        sdp[tid] = dp; sdn[tid] = dn;      // reuse as dinv
    }
    __syncthreads();
    for (int i = beg + tid; i < end; i += 512) {
        int2 r = recs[i];
        int tl = ((unsigned)r.x) >> 23;
        int slot = atomicAdd(&cur[tl], 1);
        float w = __int_as_float(r.y);
        int flag = r.x & 1;
        float nv = w * (flag ? sdn[tl] : sdp[tl]);
        int srcflag = (((r.x >> 6) & 0x1FFFF) << 8) | (flag << 7) | flag;
        edat[slot] = make_int2(srcflag, __float_as_int(nv));
    }
}

// ===========================================================================
// prep: node-parallel xs = [x*dp | x*dn] (fp16) + weight convert.
// Fully coalesced, full occupancy (was csr_build's serial tail).
// ===========================================================================
__global__ __launch_bounds__(256) void prep_kernel(
        const float* __restrict__ x,
        const float* __restrict__ dinvp, const float* __restrict__ dinvn,
        const float* __restrict__ W1p, const float* __restrict__ W1n,
        const float* __restrict__ W2p, const float* __restrict__ W2n,
        __half* __restrict__ xs, __half* __restrict__ w16, int n) {
    int idx = blockIdx.x * blockDim.x + threadIdx.x;
    int npx = n * 32;
    if (idx < npx) {
        int row = idx >> 5, jp = idx & 31;
        float2 v = *(const float2*)(x + (size_t)row * 64 + jp * 2);
        float dp = dinvp[row], dn = dinvn[row];
        __half2* xr = (__half2*)(xs + (size_t)row * 128);
        xr[jp]      = __floats2half2_rn(v.x * dp, v.y * dp);
        xr[jp + 32] = __floats2half2_rn(v.x * dn, v.y * dn);
    } else {
        int q = idx - npx;
        if (q < 16384) {
            const float* Wsrc = (q < 4096) ? W1p : (q < 8192) ? W1n
                              : (q < 12288) ? W2p : W2n;
            float2 v = *(const float2*)(Wsrc + (size_t)(q & 4095) * 2);
            ((__half2*)w16)[q] = __floats2half2_rn(v.x, v.y);
        }
    }
}

// ===========================================================================
// gatherX: layer-1 aggregation (1 row per wave, unroll 8, nt streams).
// ===========================================================================
__global__ __launch_bounds__(256) void gatherX_kernel(
        const int2* __restrict__ rowse, const int2* __restrict__ edat,
        const __half* __restrict__ xs,
        const float* __restrict__ dinvp, const float* __restrict__ dinvn,
        __half* __restrict__ agg, int n) {
    const int lane = threadIdx.x & 63;
    int t = (blockIdx.x * blockDim.x + threadIdx.x) >> 6;
    if (t >= n) return;
    t = __builtin_amdgcn_readfirstlane(t);
    const char* xB = (const char*)xs;
    int2 se = rowse[t];
    int beg = se.x, end = se.y;
    float aP[8], aN[8];
#pragma unroll
    for (int j = 0; j < 8; ++j) { aP[j] = 0.f; aN[j] = 0.f; }
    int e = beg;
    for (; e + 7 < end; e += 8) {
        unsigned long long dv[8];
#pragma unroll
        for (int j = 0; j < 8; ++j)
            dv[j] = __builtin_nontemporal_load(
                        (const unsigned long long*)(edat + e + j));
        const __half* r[8];
        float nvv[8];
        int fl[8];
#pragma unroll
        for (int j = 0; j < 8; ++j) {
            unsigned dx = (unsigned)dv[j];
            r[j]   = (const __half*)(xB + (dx & 0xFFFFFF80u));
            nvv[j] = __int_as_float((int)(dv[j] >> 32));
            fl[j]  = dx & 1;
        }
#pragma unroll
        for (int j = 0; j < 8; ++j) {
            float c = __half2float(r[j][lane]) * nvv[j];
            if (fl[j]) aN[j] += c; else aP[j] += c;
        }
    }
    for (; e + 3 < end; e += 4) {
        unsigned long long dv[4];
#pragma unroll
        for (int j = 0; j < 4; ++j)
            dv[j] = __builtin_nontemporal_load(
                        (const unsigned long long*)(edat + e + j));
#pragma unroll
        for (int j = 0; j < 4; ++j) {
            unsigned dx = (unsigned)dv[j];
            const __half* r = (const __half*)(xB + (dx & 0xFFFFFF80u));
            float c = __half2float(r[lane]) * __int_as_float((int)(dv[j] >> 32));
            if (dx & 1) aN[j] += c; else aP[j] += c;
        }
    }
    for (; e < end; ++e) {
        unsigned long long dv = __builtin_nontemporal_load(
                                    (const unsigned long long*)(edat + e));
        unsigned dx = (unsigned)dv;
        const __half* r = (const __half*)(xB + (dx & 0xFFFFFF80u));
        float c = __half2float(r[lane]) * __int_as_float((int)(dv >> 32));
        if (dx & 1) aN[0] += c; else aP[0] += c;
    }
    float accP = ((aP[0] + aP[1]) + (aP[2] + aP[3]))
               + ((aP[4] + aP[5]) + (aP[6] + aP[7]));
    float accN = ((aN[0] + aN[1]) + (aN[2] + aN[3]))
               + ((aN[4] + aN[5]) + (aN[6] + aN[7]));
    float sp = dinvp[t], sn = dinvn[t];
    accP += sp * __half2float(xs[(size_t)t * 128 + lane]);
    accN -= sn * __half2float(xs[(size_t)t * 128 + 64 + lane]);
    __builtin_nontemporal_store(__half_as_ushort((__half)accP),
        (unsigned short*)(agg + (size_t)t * 128 + lane));
    __builtin_nontemporal_store(__half_as_ushort((__half)accN),
        (unsigned short*)(agg + (size_t)t * 128 + 64 + lane));
}

// ===========================================================================
// gemm12: fused dual-layer GEMM, B-resident (round-9 verified structure).
// g2 ALIASES agg (row-local; agg reads precede g2 writes) — no __restrict__.
// ===========================================================================
__global__ __launch_bounds__(256, 2) void gemm12_mfma(
        const __half* agg,
        const __half* __restrict__ w1p, const __half* __restrict__ w1n,
        const float* __restrict__ b1p, const float* __restrict__ b1n,
        const __half* __restrict__ w2p, const __half* __restrict__ w2n,
        const float* __restrict__ dinvp, const float* __restrict__ dinvn,
        __half* g2, int n) {
    __shared__ _Float16 T[16 * LSTR];
    const int lane = threadIdx.x & 63;
    const int wv = threadIdx.x >> 6;
    const int m = lane & 15, quad = lane >> 4;
    const int t0 = 2 * wv, t1 = t0 + 1;      // this wave's two col-tiles
    const int ntile = (n + 15) >> 4;

    f16x8 B1a[4], B1b[4], B2a[4], B2b[4];
    const __half* W2 = (t0 < 4) ? w2p : w2n;
#pragma unroll
    for (int kc = 0; kc < 4; ++kc) {
        const __half* W1 = (kc < 2) ? w1p : w1n;
        const int ko = (kc & 1) * 32 + quad * 8;
        B1a[kc] = *(const f16x8*)(W1 + (size_t)(t0 * 16 + m) * 64 + ko);
        B1b[kc] = *(const f16x8*)(W1 + (size_t)(t1 * 16 + m) * 64 + ko);
        B2a[kc] = *(const f16x8*)(W2 + (size_t)((t0 & 3) * 16 + m) * 128 + kc * 32 + quad * 8);
        B2b[kc] = *(const f16x8*)(W2 + (size_t)((t1 & 3) * 16 + m) * 128 + kc * 32 + quad * 8);
    }
    const float bd0 = b1p[t0 * 16 + m] - b1n[t0 * 16 + m];
    const float bd1 = b1p[t1 * 16 + m] - b1n[t1 * 16 + m];

    int tile = blockIdx.x;
    f16x8 a1c[4];
    if (tile < ntile) {
        int arow = tile * 16 + m; if (arow > n - 1) arow = n - 1;
#pragma unroll
        for (int kc = 0; kc < 4; ++kc)
            a1c[kc] = *(const f16x8*)(agg + (size_t)arow * 128 + kc * 32 + quad * 8);
    }

    for (; tile < ntile; tile += gridDim.x) {
        const int row0 = tile * 16;
        f32x4 acc0 = (f32x4){0.f, 0.f, 0.f, 0.f};
        f32x4 acc1 = (f32x4){0.f, 0.f, 0.f, 0.f};
#pragma unroll
        for (int kc = 0; kc < 4; ++kc) {
            acc0 = __builtin_amdgcn_mfma_f32_16x16x32_f16(a1c[kc], B1a[kc], acc0, 0, 0, 0);
            acc1 = __builtin_amdgcn_mfma_f32_16x16x32_f16(a1c[kc], B1b[kc], acc1, 0, 0, 0);
        }
        float sp[4], sn[4]; int rows[4];
#pragma unroll
        for (int r = 0; r < 4; ++r) {
            int rw = row0 + quad * 4 + r;
            rows[r] = rw;
            sp[r] = (rw < n) ? dinvp[rw] : 0.f;
            sn[r] = (rw < n) ? dinvn[rw] : 0.f;
        }
#pragma unroll
        for (int r = 0; r < 4; ++r) {
            T[(quad * 4 + r) * LSTR + t0 * 16 + m] = (_Float16)fmaxf(acc0[r] + bd0, 0.f);
            T[(quad * 4 + r) * LSTR + t1 * 16 + m] = (_Float16)fmaxf(acc1[r] + bd1, 0.f);
        }
        const int ntile_i = tile + gridDim.x;
        f16x8 a1nx[4];
        if (ntile_i < ntile) {
            int arow = ntile_i * 16 + m; if (arow > n - 1) arow = n - 1;
#pragma unroll
            for (int kc = 0; kc < 4; ++kc)
                a1nx[kc] = *(const f16x8*)(agg + (size_t)arow * 128 + kc * 32 + quad * 8);
        }
        __syncthreads();
        f16x8 a2[4];
#pragma unroll
        for (int kc = 0; kc < 4; ++kc)
            a2[kc] = *(const f16x8*)(T + m * LSTR + kc * 32 + quad * 8);
        __syncthreads();
        f32x4 c0 = (f32x4){0.f, 0.f, 0.f, 0.f};
        f32x4 c1 = (f32x4){0.f, 0.f, 0.f, 0.f};
#pragma unroll
        for (int kc = 0; kc < 4; ++kc) {
            c0 = __builtin_amdgcn_mfma_f32_16x16x32_f16(a2[kc], B2a[kc], c0, 0, 0, 0);
            c1 = __builtin_amdgcn_mfma_f32_16x16x32_f16(a2[kc], B2b[kc], c1, 0, 0, 0);
        }
        const float* dsel0 = (t0 < 4) ? sp : sn;
#pragma unroll
        for (int r = 0; r < 4; ++r)
            if (rows[r] < n) {
                g2[(size_t)rows[r] * 128 + t0 * 16 + m] = (__half)(c0[r] * dsel0[r]);
                g2[(size_t)rows[r] * 128 + t1 * 16 + m] = (__half)(c1[r] * dsel0[r]);
            }
#pragma unroll
        for (int kc = 0; kc < 4; ++kc) a1c[kc] = a1nx[kc];
    }
}

// ===========================================================================
// gather64: layer-2 aggregation.
// ===========================================================================
__global__ __launch_bounds__(256) void gather64_kernel(
        const int2* __restrict__ rowse, const int2* __restrict__ edat,
        const __half* __restrict__ g2,
        const float* __restrict__ dinvp, const float* __restrict__ dinvn,
        const float* __restrict__ bp, const float* __restrict__ bn,
        float* __restrict__ out, int n) {
    const int lane = threadIdx.x & 63;
    int t = (blockIdx.x * blockDim.x + threadIdx.x) >> 6;
    if (t >= n) return;
    t = __builtin_amdgcn_readfirstlane(t);
    const char* gB = (const char*)g2;
    int2 se = rowse[t];
    int beg = se.x, end = se.y;
    float ac[8];
#pragma unroll
    for (int j = 0; j < 8; ++j) ac[j] = 0.f;
    int e = beg;
    for (; e + 7 < end; e += 8) {
        unsigned long long dv[8];
#pragma unroll
        for (int j = 0; j < 8; ++j)
            dv[j] = __builtin_nontemporal_load(
                        (const unsigned long long*)(edat + e + j));
#pragma unroll
        for (int j = 0; j < 8; ++j) {
            unsigned dx = (unsigned)dv[j];
            const __half* r = (const __half*)(gB + (dx & 0xFFFFFF80u));
            ac[j] += __half2float(r[lane]) * __int_as_float((int)(dv[j] >> 32));
        }
    }
    for (; e + 3 < end; e += 4) {
        unsigned long long dv[4];
#pragma unroll
        for (int j = 0; j < 4; ++j)
            dv[j] = __builtin_nontemporal_load(
                        (const unsigned long long*)(edat + e + j));
#pragma unroll
        for (int j = 0; j < 4; ++j) {
            unsigned dx = (unsigned)dv[j];
            const __half* r = (const __half*)(gB + (dx & 0xFFFFFF80u));
            ac[j] += __half2float(r[lane]) * __int_as_float((int)(dv[j] >> 32));
        }
    }
    for (; e < end; ++e) {
        unsigned long long dv = __builtin_nontemporal_load(
                                    (const unsigned long long*)(edat + e));
        unsigned dx = (unsigned)dv;
        const __half* r = (const __half*)(gB + (dx & 0xFFFFFF80u));
        ac[0] += __half2float(r[lane]) * __int_as_float((int)(dv >> 32));
    }
    float acc = ((ac[0] + ac[1]) + (ac[2] + ac[3]))
              + ((ac[4] + ac[5]) + (ac[6] + ac[7]));
    const float dp = dinvp[t], dn = dinvn[t];
    float hpv = __half2float(g2[(size_t)t * 128 + lane]);
    float hnv = __half2float(g2[(size_t)t * 128 + 64 + lane]);
    float o = acc + hpv * dp + bp[lane] - hnv * dn - bn[lane];
    __builtin_nontemporal_store(fmaxf(o, 0.f), out + (size_t)t * 64 + lane);
}

// ---------------------------------------------------------------------------
extern "C" void kernel_launch(void* const* d_in, const int* in_sizes, int n_in,
                              void* d_out, int out_size, void* d_ws, size_t ws_size,
                              hipStream_t stream) {
    const float* x   = (const float*)d_in[0];
    const int*   ei  = (const int*)d_in[1];
    const float* ew  = (const float*)d_in[2];
    const float* W1p = (const float*)d_in[3];
    const float* b1p = (const float*)d_in[4];
    const float* W1n = (const float*)d_in[5];
    const float* b1n = (const float*)d_in[6];
    const float* W2p = (const float*)d_in[7];
    const float* b2p = (const float*)d_in[8];
    const float* W2n = (const float*)d_in[9];
    const float* b2n = (const float*)d_in[10];

    const int E = in_sizes[2];
    const int n = in_sizes[0] / 64;  // IN = 64
    const int nb = (n + BTGT - 1) >> BSH;
    const int* src = ei;
    const int* tgt = ei + E;

    // ws layout (4B units): cnt_pad[4096] | rowse[2n] | dinvp[n] | dinvn[n] |
    //   xs[64n] | w16[16384] | recs[2*nb*CAP] | edat[2*nb*CAP] | agg[64n].
    //   g2 aliases agg.  ~85 MB.
    int* wsi     = (int*)d_ws;
    int* cnt_pad = wsi;
    size_t o = 4096;
    int2*  rowse  = (int2*)(wsi + o);   o += 2 * (size_t)n;
    float* dinvp  = (float*)(wsi + o);  o += n;
    float* dinvn  = (float*)(wsi + o);  o += n;
    o = (o + 3) & ~(size_t)3;
    __half* xs  = (__half*)(wsi + o);   o += (size_t)n * 64;   // 128 halves/row
    __half* w16 = (__half*)(wsi + o);   o += 16384;
    __half* w1p16 = w16, *w1n16 = w16 + 8192, *w2p16 = w16 + 16384, *w2n16 = w16 + 24576;
    int2* recs = (int2*)(wsi + o);      o += 2 * (size_t)nb * CAP;
    int2* edat = (int2*)(wsi + o);      o += 2 * (size_t)nb * CAP;
    __half* agg = (__half*)(wsi + o);   o += (size_t)n * 64;
    __half* g2  = agg;                  // aliased (row-local in gemm12)
    float*  out = (float*)d_out;

    hipMemsetAsync(cnt_pad, 0, 4096 * sizeof(int), stream);

    const int gridA = (E + ACHUNK - 1) / ACHUNK;
    const int gridP = (n * 32 + 16384 + TPB - 1) / TPB;
    const int gridW = (n * 64 + TPB - 1) / TPB;
    const int ntile = (n + 15) / 16;
    const int gridF = (ntile < GGRID) ? ntile : GGRID;

    bucket_scatter_kernel<<<gridA, TPB, 0, stream>>>(tgt, src, ew, cnt_pad, recs, E);
    csr_build_kernel<<<nb, 512, 0, stream>>>(cnt_pad, recs, rowse, edat,
                                             dinvp, dinvn, n);
    prep_kernel<<<gridP, TPB, 0, stream>>>(x, dinvp, dinvn,
                                           W1p, W1n, W2p, W2n, xs, w16, n);
    gatherX_kernel<<<gridW, TPB, 0, stream>>>(rowse, edat, xs, dinvp, dinvn, agg, n);
    gemm12_mfma<<<gridF, TPB, 0, stream>>>(agg, w1p16, w1n16, b1p, b1n,
                                           w2p16, w2n16, dinvp, dinvn, g2, n);
    gather64_kernel<<<gridW, TPB, 0, stream>>>(rowse, edat, g2, dinvp, dinvn,
                                               b2p, b2n, out, n);
}